// Round 7
// baseline (607.821 us; speedup 1.0000x reference)
//
#include <hip/hip_runtime.h>
#include <hip/hip_bf16.h>

using bf16 = __hip_bfloat16;
typedef __attribute__((ext_vector_type(8))) short bf16x8;   // 8 bf16 = 4 VGPRs
typedef __attribute__((ext_vector_type(4))) float f32x4;

__device__ inline float u2f(unsigned int u) { return __uint_as_float(u << 16); }
__device__ inline float toF(float x) { return x; }
__device__ inline float toF(bf16 x) { return __bfloat162float(x); }
__device__ inline void storeO(float* p, float v) { *p = v; }
__device__ inline void storeO(bf16* p, float v) { *p = __float2bfloat16(v); }

// async global->LDS, 16B per lane. LDS dest must be wave-uniform base
// (HW adds lane*16); global src is per-lane.
__device__ inline void gload_lds16(const void* g, void* l) {
    __builtin_amdgcn_global_load_lds(
        (const __attribute__((address_space(1))) void*)g,
        (__attribute__((address_space(3))) void*)l, 16, 0, 0);
}

// workgroup barrier that does NOT drain vmcnt (prefetch loads stay in
// flight). lgkmcnt(0) orders this wave's LDS ops; raw s_barrier syncs.
__device__ inline void wgbar() {
    asm volatile("s_waitcnt lgkmcnt(0)" ::: "memory");
    __builtin_amdgcn_s_barrier();
    asm volatile("" ::: "memory");
}

// byte offset into a [64][128B] LDS tile with XOR swizzle (bank-conflict fix)
__device__ inline int swzb(int row, int bcol) {
    return row * 128 + (bcol ^ (((row ^ (row >> 3)) & 7) << 4));
}

// ---------------------------------------------------------------- transpose
// fp32 [R,C] -> bf16 [C,R]. R, C multiples of 32. block = 256 (32x8 logical).
__global__ __launch_bounds__(256) void transpose_k(const float* __restrict__ in,
                                                   bf16* __restrict__ out,
                                                   int R, int C) {
    __shared__ float tile[32][33];
    const int c0 = blockIdx.x * 32, r0 = blockIdx.y * 32;
    const int tx = threadIdx.x & 31, ty = threadIdx.x >> 5;
#pragma unroll
    for (int i = 0; i < 32; i += 8)
        tile[ty + i][tx] = in[(size_t)(r0 + ty + i) * C + (c0 + tx)];
    __syncthreads();
#pragma unroll
    for (int i = 0; i < 32; i += 8)
        out[(size_t)(c0 + ty + i) * R + (r0 + tx)] = __float2bfloat16(tile[tx][ty + i]);
}

// fused QKV weight transpose: z selects wq/wk/wv -> wqkvT + z*1M (all 1024^2)
__global__ __launch_bounds__(256) void qkvT_k(const float* __restrict__ wq,
                                              const float* __restrict__ wk,
                                              const float* __restrict__ wv,
                                              bf16* __restrict__ out) {
    __shared__ float tile[32][33];
    const float* in = blockIdx.z == 0 ? wq : (blockIdx.z == 1 ? wk : wv);
    bf16* o = out + (size_t)blockIdx.z * 1024 * 1024;
    const int c0 = blockIdx.x * 32, r0 = blockIdx.y * 32;
    const int tx = threadIdx.x & 31, ty = threadIdx.x >> 5;
#pragma unroll
    for (int i = 0; i < 32; i += 8)
        tile[ty + i][tx] = in[(size_t)(r0 + ty + i) * 1024 + (c0 + tx)];
    __syncthreads();
#pragma unroll
    for (int i = 0; i < 32; i += 8)
        o[(size_t)(c0 + ty + i) * 1024 + (r0 + tx)] = __float2bfloat16(tile[tx][ty + i]);
}

// concat 3x1024 fp32 biases -> [3072]
__global__ __launch_bounds__(256) void catb_k(const float* __restrict__ a,
                                              const float* __restrict__ b,
                                              const float* __restrict__ c,
                                              float* __restrict__ o) {
    const int t = blockIdx.x * 256 + threadIdx.x;
    const float* s = t < 1024 ? a : (t < 2048 ? b : c);
    o[t] = s[t & 1023];
}

// ---------------------------------------------------------------- layernorm
__device__ inline float waveRedSum(float x) {
#pragma unroll
    for (int off = 32; off; off >>= 1) x += __shfl_xor(x, off, 64);
    return x;
}

template <typename T>
__global__ __launch_bounds__(256) void layernorm_k(const T* __restrict__ in,
                                                   const float* __restrict__ g,
                                                   const float* __restrict__ bta,
                                                   bf16* __restrict__ out) {
    const int row = blockIdx.x, t = threadIdx.x;
    const int lane = t & 63, wid = t >> 6;
    const T* xr = in + (size_t)row * 1024;
    float v0, v1, v2, v3;
    if constexpr (sizeof(T) == 4) {
        float4 u = ((const float4*)xr)[t];
        v0 = u.x; v1 = u.y; v2 = u.z; v3 = u.w;
    } else {
        ushort4 u = ((const ushort4*)xr)[t];
        v0 = u2f(u.x); v1 = u2f(u.y); v2 = u2f(u.z); v3 = u2f(u.w);
    }
    __shared__ float red[8];
    float s = waveRedSum(v0 + v1 + v2 + v3);
    if (lane == 0) red[wid] = s;
    __syncthreads();
    float mu = (red[0] + red[1] + red[2] + red[3]) * (1.f / 1024.f);
    float d0 = v0 - mu, d1 = v1 - mu, d2 = v2 - mu, d3 = v3 - mu;
    float ss = waveRedSum(d0 * d0 + d1 * d1 + d2 * d2 + d3 * d3);
    if (lane == 0) red[4 + wid] = ss;
    __syncthreads();
    float var = (red[4] + red[5] + red[6] + red[7]) * (1.f / 1024.f);
    float inv = rsqrtf(var + 1e-6f);
    const int c = t * 4;
    bf16* orow = out + (size_t)row * 1024;
    orow[c + 0] = __float2bfloat16(d0 * inv * g[c + 0] + bta[c + 0]);
    orow[c + 1] = __float2bfloat16(d1 * inv * g[c + 1] + bta[c + 1]);
    orow[c + 2] = __float2bfloat16(d2 * inv * g[c + 2] + bta[c + 2]);
    orow[c + 3] = __float2bfloat16(d3 * inv * g[c + 3] + bta[c + 3]);
}

// ---------------------------------------------------------------- MFMA GEMM
// C[M,N] = A[M,K](bf16,[M][K]) @ B(bf16,[N][K] row-stride ldB) + bias.
// 128x128 tile/block, 256 thr = 2x2 waves of 64x64 (4x4 mfma 16x16x32).
// 4-buffer ring, prefetch distance 3, COUNTED vmcnt(8/4/0) (T3+T4): the
// oldest tile's loads were issued 3 K-steps ago -> wait is ~free. 64KB LDS
// -> exactly 2 blocks/CU, so the machine round is 512 block-slots: all our
// grids (512/1024/1536) pack into WHOLE rounds (R6 lesson: per-CU rate is
// insensitive to blocks/CU in 2-5; round quantization is what costs).
// 1-D grid + bijective XCD swizzle (T1).
template <int GELU, int RES, int ACC, typename RT, typename OT>
__global__ __launch_bounds__(256) void mgemm_k(const bf16* __restrict__ A,
                                               const bf16* __restrict__ B, int ldB,
                                               const float* __restrict__ bias,
                                               const RT* __restrict__ resid,
                                               OT* C, int M, int N, int K, int gx) {
    __shared__ bf16 As[4 * 128 * 32];
    __shared__ bf16 Bs[4 * 128 * 32];
    const int tid = threadIdx.x;
    const int lane = tid & 63, wid = tid >> 6;
    const int l16 = lane & 15, quad = lane >> 4;
    const int wm = (wid >> 1) * 64, wn = (wid & 1) * 64;
    const int nwg = gridDim.x;
    const int wg = ((blockIdx.x & 7) * (nwg >> 3)) + (blockIdx.x >> 3);
    const int m0 = (wg / gx) * 128, n0 = (wg % gx) * 128;

    const int r0 = tid >> 2, sc0 = tid & 3;
    const int lc0 = sc0 ^ ((r0 >> 1) & 3);
    const int r1 = r0 + 64;
    const int lc1 = sc0 ^ ((r1 >> 1) & 3);
    const bf16* gA0 = A + (size_t)(m0 + r0) * K + lc0 * 8;
    const bf16* gA1 = A + (size_t)(m0 + r1) * K + lc1 * 8;
    const bf16* gB0 = B + (size_t)(n0 + r0) * ldB + lc0 * 8;
    const bf16* gB1 = B + (size_t)(n0 + r1) * ldB + lc1 * 8;
    char* asb = (char*)As;
    char* bsb = (char*)Bs;
    const int lb0 = wid * 1024, lb1 = 4096 + wid * 1024;  // wave-uniform bases
    const int rdsw = (quad ^ ((l16 >> 1) & 3)) * 16;      // frag-read swizzle

    f32x4 acc[4][4] = {};
    const int nT = K >> 5;
    // prologue: stage tiles 0..2 into buffers 0..2 (12 vm ops in flight)
    const int npro = nT < 3 ? nT : 3;
    for (int p = 0; p < npro; ++p) {
        char* ab = asb + p * 8192;
        char* bb = bsb + p * 8192;
        const int ko = p * 32;
        gload_lds16(gA0 + ko, ab + lb0);
        gload_lds16(gA1 + ko, ab + lb1);
        gload_lds16(gB0 + ko, bb + lb0);
        gload_lds16(gB1 + ko, bb + lb1);
    }
    int issued = npro;
    for (int t = 0; t < nT; ++t) {
        const int rem = issued - t - 1;        // tiles in flight beyond t
        if (rem >= 2)      asm volatile("s_waitcnt vmcnt(8)" ::: "memory");
        else if (rem == 1) asm volatile("s_waitcnt vmcnt(4)" ::: "memory");
        else               asm volatile("s_waitcnt vmcnt(0)" ::: "memory");
        __builtin_amdgcn_s_barrier();          // tile t staged for all waves
        if (issued < nT) {                     // refill: 3 tiles in flight
            char* ab = asb + (issued & 3) * 8192;
            char* bb = bsb + (issued & 3) * 8192;
            const int ko = issued * 32;
            gload_lds16(gA0 + ko, ab + lb0);
            gload_lds16(gA1 + ko, ab + lb1);
            gload_lds16(gB0 + ko, bb + lb0);
            gload_lds16(gB1 + ko, bb + lb1);
            ++issued;
        }
        const char* ar = asb + (t & 3) * 8192;
        const char* br = bsb + (t & 3) * 8192;
        bf16x8 a[4], b[4];
#pragma unroll
        for (int i = 0; i < 4; ++i)
            a[i] = *(const bf16x8*)(ar + (wm + i * 16 + l16) * 64 + rdsw);
#pragma unroll
        for (int i = 0; i < 4; ++i)
            b[i] = *(const bf16x8*)(br + (wn + i * 16 + l16) * 64 + rdsw);
        __builtin_amdgcn_s_setprio(1);
#pragma unroll
        for (int mi = 0; mi < 4; ++mi)
#pragma unroll
            for (int ni = 0; ni < 4; ++ni)
                acc[mi][ni] = __builtin_amdgcn_mfma_f32_16x16x32_bf16(
                    a[mi], b[ni], acc[mi][ni], 0, 0, 0);
        __builtin_amdgcn_s_setprio(0);
    }
#pragma unroll
    for (int mi = 0; mi < 4; ++mi) {
#pragma unroll
        for (int ni = 0; ni < 4; ++ni) {
            const int col = n0 + wn + ni * 16 + l16;
            const float bv = bias ? bias[col] : 0.f;
#pragma unroll
            for (int r = 0; r < 4; ++r) {
                const int row = m0 + wm + mi * 16 + quad * 4 + r;
                float val = acc[mi][ni][r] + bv;
                if (GELU) {
                    float z = 0.7978845608028654f * (val + 0.044715f * val * val * val);
                    float th = 1.f - 2.f / (__expf(2.f * z) + 1.f);
                    val = 0.5f * val * (1.f + th);
                }
                const size_t idx = (size_t)row * N + col;
                if (RES) val += toF(resid[idx]);
                if (ACC) val += toF(C[idx]);
                storeO(&C[idx], val);
            }
        }
    }
}

// ---------------------------------------------------------------- attention
// MFMA flash attention, register-staged K/V prefetch (T14), defer-max (T13),
// setprio (T5). 1-D grid 512: blocks c and c+256 (same CU under round-robin)
// get COMPLEMENTARY causal lengths so every CU's workload is ~equal.
__global__ __launch_bounds__(256) void attn_k(const bf16* __restrict__ q,
                                              const bf16* __restrict__ k,
                                              const bf16* __restrict__ v,
                                              bf16* __restrict__ o, int rs) {
    const int bid = blockIdx.x;
    const int u = bid & 255, top = bid >> 8;
    const int xx = u & 3;
    const int h = (u >> 2) & 15;
    const int b = top * 4 + (u >> 6);
    const int qi = top ? 3 - xx : xx;
    const int qblock = qi * 256;
    const int tid = threadIdx.x;
    const int wave = tid >> 6, lane = tid & 63;
    const int l16 = lane & 15, quad = lane >> 4;
    const int q0w = qblock + wave * 64;

    __shared__ __align__(16) bf16 Kl[64 * 64];       // [k][d] swizzled
    __shared__ __align__(16) bf16 Vt[64 * 64];       // [d][k] swizzled
    __shared__ __align__(16) bf16 Pl[4 * 64 * 64];   // per-wave [q][k] swizzled
    __shared__ __align__(16) float sc[4][64];        // per-wave per-q scratch

    bf16x8 qf[4][2];
#pragma unroll
    for (int ni = 0; ni < 4; ++ni) {
        const int row = q0w + ni * 16 + l16;
        const bf16* qp = q + ((size_t)b * 1024 + row) * rs + h * 64;
#pragma unroll
        for (int kc = 0; kc < 2; ++kc)
            qf[ni][kc] = *(const bf16x8*)(qp + kc * 32 + quad * 8);
    }

    f32x4 acc[4][4] = {};     // O: row q = mi*16+quad*4+r, col d = ni*16+l16
    float mrun[4], lrun[4];
#pragma unroll
    for (int ni = 0; ni < 4; ++ni) { mrun[ni] = -1e30f; lrun[ni] = 0.f; }

    const int NT = qi * 4 + 4;
    const int myNT = qi * 4 + wave + 1;

    const int kr_ = tid >> 3, kch = tid & 7;              // K rows kr_, kr_+32
    const int vr_ = (tid >> 3) * 2, vdb = (tid & 7) * 8;  // V rows vr_, vr_+1
    uint4 kA, kB, vA, vB;
    {   // prefetch tile 0
        const size_t gk = ((size_t)b * 1024 + 0 + kr_) * rs + h * 64 + kch * 8;
        kA = *(const uint4*)(k + gk);
        kB = *(const uint4*)(k + gk + (size_t)32 * rs);
        const size_t gv = ((size_t)b * 1024 + 0 + vr_) * rs + h * 64 + vdb;
        vA = *(const uint4*)(v + gv);
        vB = *(const uint4*)(v + gv + rs);
    }

    for (int t = 0; t < NT; ++t) {
        wgbar();   // all waves done reading Kl/Vt from previous tile
        // ---- write prefetched K (row-major, swizzled) ----
        *(uint4*)((char*)Kl + swzb(kr_, kch * 16)) = kA;
        *(uint4*)((char*)Kl + swzb(kr_ + 32, kch * 16)) = kB;
        // ---- write prefetched V transposed (Vt[d][k], swizzled) ----
        {
            const unsigned aw[4] = {vA.x, vA.y, vA.z, vA.w};
            const unsigned bw[4] = {vB.x, vB.y, vB.z, vB.w};
#pragma unroll
            for (int j = 0; j < 8; ++j) {
                const unsigned lo = (aw[j >> 1] >> ((j & 1) * 16)) & 0xffffu;
                const unsigned hi = (bw[j >> 1] >> ((j & 1) * 16)) & 0xffffu;
                *(unsigned*)((char*)Vt + swzb(vdb + j, vr_ * 2)) = lo | (hi << 16);
            }
        }
        // ---- issue next tile's global loads (fly across compute) ----
        if (t + 1 < NT) {
            const int j1 = (t + 1) * 64;
            const size_t gk = ((size_t)b * 1024 + j1 + kr_) * rs + h * 64 + kch * 8;
            kA = *(const uint4*)(k + gk);
            kB = *(const uint4*)(k + gk + (size_t)32 * rs);
            const size_t gv = ((size_t)b * 1024 + j1 + vr_) * rs + h * 64 + vdb;
            vA = *(const uint4*)(v + gv);
            vB = *(const uint4*)(v + gv + rs);
        }
        wgbar();   // staged tile visible to all waves
        if (t < myNT) {
            const int j0 = t * 64;
            // ---- S^T = K @ Q^T ----
            f32x4 st[4][4] = {};
#pragma unroll
            for (int kc = 0; kc < 2; ++kc) {
                bf16x8 kf[4];
#pragma unroll
                for (int mi = 0; mi < 4; ++mi)
                    kf[mi] = *(const bf16x8*)((char*)Kl +
                             swzb(mi * 16 + l16, kc * 64 + quad * 16));
                __builtin_amdgcn_s_setprio(1);
#pragma unroll
                for (int mi = 0; mi < 4; ++mi)
#pragma unroll
                    for (int ni = 0; ni < 4; ++ni)
                        st[mi][ni] = __builtin_amdgcn_mfma_f32_16x16x32_bf16(
                            kf[mi], qf[ni][kc], st[mi][ni], 0, 0, 0);
                __builtin_amdgcn_s_setprio(0);
            }
            if (j0 == q0w) {  // causal mask, diagonal tile only
#pragma unroll
                for (int mi = 0; mi < 4; ++mi)
#pragma unroll
                    for (int ni = 0; ni < 4; ++ni)
#pragma unroll
                        for (int r = 0; r < 4; ++r)
                            if (mi * 16 + quad * 4 + r > ni * 16 + l16)
                                st[mi][ni][r] = -1e30f;
            }
            // ---- tile max per q (tree + cross-quad reduce) ----
            float mx[4];
#pragma unroll
            for (int ni = 0; ni < 4; ++ni) {
                float a0 = fmaxf(st[0][ni][0], st[0][ni][1]);
                float a1 = fmaxf(st[0][ni][2], st[0][ni][3]);
                float a2 = fmaxf(st[1][ni][0], st[1][ni][1]);
                float a3 = fmaxf(st[1][ni][2], st[1][ni][3]);
                float a4 = fmaxf(st[2][ni][0], st[2][ni][1]);
                float a5 = fmaxf(st[2][ni][2], st[2][ni][3]);
                float a6 = fmaxf(st[3][ni][0], st[3][ni][1]);
                float a7 = fmaxf(st[3][ni][2], st[3][ni][3]);
                float m_ = fmaxf(fmaxf(fmaxf(a0, a1), fmaxf(a2, a3)),
                                 fmaxf(fmaxf(a4, a5), fmaxf(a6, a7)));
                m_ = fmaxf(m_, __shfl_xor(m_, 16, 64));
                m_ = fmaxf(m_, __shfl_xor(m_, 32, 64));
                mx[ni] = m_;
            }
            // ---- defer-max (T13): rescale only if growth > 64 raw ----
            const bool need = (mx[0] > mrun[0] + 64.f) | (mx[1] > mrun[1] + 64.f) |
                              (mx[2] > mrun[2] + 64.f) | (mx[3] > mrun[3] + 64.f);
            if (__any(need)) {
                float fac[4];
#pragma unroll
                for (int ni = 0; ni < 4; ++ni) {
                    const float nm = (mx[ni] > mrun[ni] + 64.f) ? mx[ni] : mrun[ni];
                    fac[ni] = __expf((mrun[ni] - nm) * 0.125f);
                    mrun[ni] = nm;
                    lrun[ni] *= fac[ni];
                }
                if (quad == 0)
#pragma unroll
                    for (int ni = 0; ni < 4; ++ni) sc[wave][ni * 16 + l16] = fac[ni];
#pragma unroll
                for (int mi = 0; mi < 4; ++mi) {
                    const f32x4 f4 = *(const f32x4*)&sc[wave][mi * 16 + quad * 4];
#pragma unroll
                    for (int ni = 0; ni < 4; ++ni)
#pragma unroll
                        for (int r = 0; r < 4; ++r) acc[mi][ni][r] *= f4[r];
                }
            }
            // ---- exp + sum (4 parallel chains, tree finish) ----
#pragma unroll
            for (int ni = 0; ni < 4; ++ni) {
                const float mm = mrun[ni];
                float t0 = 0.f, t1 = 0.f, t2 = 0.f, t3 = 0.f;
#pragma unroll
                for (int mi = 0; mi < 4; ++mi) {
                    float p0 = __expf((st[mi][ni][0] - mm) * 0.125f);
                    float p1 = __expf((st[mi][ni][1] - mm) * 0.125f);
                    float p2 = __expf((st[mi][ni][2] - mm) * 0.125f);
                    float p3 = __expf((st[mi][ni][3] - mm) * 0.125f);
                    st[mi][ni][0] = p0; st[mi][ni][1] = p1;
                    st[mi][ni][2] = p2; st[mi][ni][3] = p3;
                    t0 += p0; t1 += p1; t2 += p2; t3 += p3;
                }
                float ls = (t0 + t1) + (t2 + t3);
                ls += __shfl_xor(ls, 16, 64);
                ls += __shfl_xor(ls, 32, 64);
                lrun[ni] += ls;
            }
            // ---- write P to per-wave LDS [q][k] (b64 packed, swizzled) ----
            char* Pb = (char*)Pl + wave * 8192;
#pragma unroll
            for (int ni = 0; ni < 4; ++ni) {
                const int qrow = ni * 16 + l16;
#pragma unroll
                for (int mi = 0; mi < 4; ++mi) {
                    union { bf16 bv[4]; uint2 u2; } pk;
#pragma unroll
                    for (int r = 0; r < 4; ++r)
                        pk.bv[r] = __float2bfloat16(st[mi][ni][r]);
                    *(uint2*)(Pb + swzb(qrow, mi * 32 + quad * 8)) = pk.u2;
                }
            }
            // ---- O += P @ V ----
#pragma unroll
            for (int kc = 0; kc < 2; ++kc) {
                bf16x8 pf[4], vf[4];
#pragma unroll
                for (int mi = 0; mi < 4; ++mi)
                    pf[mi] = *(const bf16x8*)(Pb +
                             swzb(mi * 16 + l16, kc * 64 + quad * 16));
#pragma unroll
                for (int ni = 0; ni < 4; ++ni)
                    vf[ni] = *(const bf16x8*)((char*)Vt +
                             swzb(ni * 16 + l16, kc * 64 + quad * 16));
                __builtin_amdgcn_s_setprio(1);
#pragma unroll
                for (int mi = 0; mi < 4; ++mi)
#pragma unroll
                    for (int ni = 0; ni < 4; ++ni)
                        acc[mi][ni] = __builtin_amdgcn_mfma_f32_16x16x32_bf16(
                            pf[mi], vf[ni], acc[mi][ni], 0, 0, 0);
                __builtin_amdgcn_s_setprio(0);
            }
        }
    }
    if (quad == 0)
#pragma unroll
        for (int ni = 0; ni < 4; ++ni) sc[wave][ni * 16 + l16] = lrun[ni];
#pragma unroll
    for (int mi = 0; mi < 4; ++mi) {
        const f32x4 l4 = *(const f32x4*)&sc[wave][mi * 16 + quad * 4];
#pragma unroll
        for (int r = 0; r < 4; ++r) {
            const float inv = 1.f / l4[r];
            const int row = q0w + mi * 16 + quad * 4 + r;
            bf16* orow = o + ((size_t)b * 1024 + row) * 1024 + h * 64;
#pragma unroll
            for (int ni = 0; ni < 4; ++ni)
                orow[ni * 16 + l16] = __float2bfloat16(acc[mi][ni][r] * inv);
        }
    }
}

// ---------------------------------------------------------------- launch
extern "C" void kernel_launch(void* const* d_in, const int* in_sizes, int n_in,
                              void* d_out, int out_size, void* d_ws, size_t ws_size,
                              hipStream_t stream) {
    (void)out_size; (void)ws_size;
    const float* x = (const float*)d_in[0];
    const int base = (n_in >= 18 && in_sizes[1] > 4096) ? 2 : 1;  // skip mask
    const float* ln1s = (const float*)d_in[base + 0];
    const float* ln1b = (const float*)d_in[base + 1];
    const float* wq   = (const float*)d_in[base + 2];
    const float* bq   = (const float*)d_in[base + 3];
    const float* wk   = (const float*)d_in[base + 4];
    const float* bk   = (const float*)d_in[base + 5];
    const float* wv   = (const float*)d_in[base + 6];
    const float* bv   = (const float*)d_in[base + 7];
    const float* wo   = (const float*)d_in[base + 8];
    const float* bo   = (const float*)d_in[base + 9];
    const float* ln2s = (const float*)d_in[base + 10];
    const float* ln2b = (const float*)d_in[base + 11];
    const float* w1   = (const float*)d_in[base + 12];
    const float* b1   = (const float*)d_in[base + 13];
    const float* w2   = (const float*)d_in[base + 14];
    const float* b2   = (const float*)d_in[base + 15];
    float* out = (float*)d_out;   // fp32 output (also used as scratch)

    // Workspace map (64MB), phase-disjoint lifetimes:
    //   ws[0,16)  h (LN1) -> ao (attn out) -> h2 (LN2 out)
    //   ws[16,64) qkv [8192][3072] bf16 -> woT[16,18) -> f1c[16,48)
    //   ws[48,56) w1T  (after attn)      ws[56,64) w2T
    // d_out (32MB fp32) as scratch early:
    //   out[0,6MB) wqkvT bf16 [3072][1024]; out[8MB) bqkv [3072] fp32
    //   -> x2 fp32 (wo GEMM, residual) -> final output (FFN2 ACC)
    char* ws = (char*)d_ws;
    char* oc = (char*)d_out;
    const size_t MB = 1ull << 20;
    bf16* h     = (bf16*)(ws + 0 * MB);
    bf16* qkv   = (bf16*)(ws + 16 * MB);
    bf16* ao    = (bf16*)(ws + 0 * MB);
    bf16* h2    = (bf16*)(ws + 0 * MB);
    bf16* woT   = (bf16*)(ws + 16 * MB);
    bf16* f1c   = (bf16*)(ws + 16 * MB);   // [8192][2048] bf16, 32MB
    bf16* w1T   = (bf16*)(ws + 48 * MB);
    bf16* w2T   = (bf16*)(ws + 56 * MB);
    bf16* wqkvT = (bf16*)(oc + 0 * MB);
    float* bqkv = (float*)(oc + 8 * MB);

    const dim3 tb(256);

    layernorm_k<float><<<8192, tb, 0, stream>>>(x, ln1s, ln1b, h);
    qkvT_k<<<dim3(32, 32, 3), tb, 0, stream>>>(wq, wk, wv, wqkvT);
    catb_k<<<12, tb, 0, stream>>>(bq, bk, bv, bqkv);
    // fused QKV: [8192][3072] = h @ wqkvT   (128x128 tiles: 64x24 = 1536 wg)
    mgemm_k<0, 0, 0, float, bf16><<<1536, tb, 0, stream>>>(
        h, wqkvT, 1024, bqkv, nullptr, qkv, 8192, 3072, 1024, 24);
    attn_k<<<512, tb, 0, stream>>>(qkv, qkv + 1024, qkv + 2048, ao, 3072);
    // qkv dead: transpose remaining weights
    transpose_k<<<dim3(32, 32), tb, 0, stream>>>(wo, woT, 1024, 1024);
    transpose_k<<<dim3(128, 32), tb, 0, stream>>>(w1, w1T, 1024, 4096);
    transpose_k<<<dim3(32, 128), tb, 0, stream>>>(w2, w2T, 4096, 1024);
    // x2 = ao @ woT + bo + x  -> fp32 directly into out (residual stream)
    mgemm_k<0, 1, 0, float, float><<<512, tb, 0, stream>>>(
        ao, woT, 1024, bo, x, out, 8192, 1024, 1024, 8);
    layernorm_k<float><<<8192, tb, 0, stream>>>(out, ln2s, ln2b, h2);
    // FFN in 2 chunks of 2048; FFN2 accumulates onto out (holds x2)
    for (int c = 0; c < 2; ++c) {
        mgemm_k<1, 0, 0, float, bf16><<<1024, tb, 0, stream>>>(
            h2, w1T + (size_t)c * 2048 * 1024, 1024, b1 + c * 2048, nullptr,
            f1c, 8192, 2048, 1024, 16);
        mgemm_k<0, 0, 1, float, float><<<512, tb, 0, stream>>>(
            f1c, w2T + c * 2048, 4096, c ? nullptr : b2, nullptr,
            out, 8192, 1024, 2048, 8);
    }
}

// Round 8
// 587.300 us; speedup vs baseline: 1.0349x; 1.0349x over previous
//
#include <hip/hip_runtime.h>
#include <hip/hip_bf16.h>

using bf16 = __hip_bfloat16;
typedef __attribute__((ext_vector_type(8))) short bf16x8;   // 8 bf16 = 4 VGPRs
typedef __attribute__((ext_vector_type(4))) float f32x4;

__device__ inline float u2f(unsigned int u) { return __uint_as_float(u << 16); }
__device__ inline float toF(float x) { return x; }
__device__ inline float toF(bf16 x) { return __bfloat162float(x); }
__device__ inline void storeO(float* p, float v) { *p = v; }
__device__ inline void storeO(bf16* p, float v) { *p = __float2bfloat16(v); }

// async global->LDS, 16B per lane. LDS dest must be wave-uniform base
// (HW adds lane*16); global src is per-lane.
__device__ inline void gload_lds16(const void* g, void* l) {
    __builtin_amdgcn_global_load_lds(
        (const __attribute__((address_space(1))) void*)g,
        (__attribute__((address_space(3))) void*)l, 16, 0, 0);
}

// workgroup barrier that does NOT drain vmcnt (prefetch loads stay in
// flight). lgkmcnt(0) orders this wave's LDS ops; raw s_barrier syncs.
__device__ inline void wgbar() {
    asm volatile("s_waitcnt lgkmcnt(0)" ::: "memory");
    __builtin_amdgcn_s_barrier();
    asm volatile("" ::: "memory");
}

// byte offset into a [64][128B] LDS tile with XOR swizzle (bank-conflict fix)
__device__ inline int swzb(int row, int bcol) {
    return row * 128 + (bcol ^ (((row ^ (row >> 3)) & 7) << 4));
}

// ---------------------------------------------------------------- transposes
// fused QKV weight transpose: z selects wq/wk/wv -> wqkvT + z*1M (all 1024^2)
__global__ __launch_bounds__(256) void qkvT_k(const float* __restrict__ wq,
                                              const float* __restrict__ wk,
                                              const float* __restrict__ wv,
                                              bf16* __restrict__ out) {
    __shared__ float tile[32][33];
    const float* in = blockIdx.z == 0 ? wq : (blockIdx.z == 1 ? wk : wv);
    bf16* o = out + (size_t)blockIdx.z * 1024 * 1024;
    const int c0 = blockIdx.x * 32, r0 = blockIdx.y * 32;
    const int tx = threadIdx.x & 31, ty = threadIdx.x >> 5;
#pragma unroll
    for (int i = 0; i < 32; i += 8)
        tile[ty + i][tx] = in[(size_t)(r0 + ty + i) * 1024 + (c0 + tx)];
    __syncthreads();
#pragma unroll
    for (int i = 0; i < 32; i += 8)
        o[(size_t)(c0 + ty + i) * 1024 + (r0 + tx)] = __float2bfloat16(tile[tx][ty + i]);
}

// batched transpose of wo (1024x1024), w1 (1024x4096), w2 (4096x1024):
// fp32 [R,C] -> bf16 [C,R], one 1-D launch (9216 tile-blocks total).
__global__ __launch_bounds__(256) void wT_k(const float* __restrict__ wo,
                                            const float* __restrict__ w1,
                                            const float* __restrict__ w2,
                                            bf16* __restrict__ woT,
                                            bf16* __restrict__ w1T,
                                            bf16* __restrict__ w2T) {
    __shared__ float tile[32][33];
    const int bid = blockIdx.x;
    const float* in; bf16* out; int C, t;
    if (bid < 1024)      { in = wo; out = woT; C = 1024; t = bid; }
    else if (bid < 5120) { in = w1; out = w1T; C = 4096; t = bid - 1024; }
    else                 { in = w2; out = w2T; C = 1024; t = bid - 5120; }
    const int R = (bid < 1024) ? 1024 : (bid < 5120 ? 1024 : 4096);
    const int ntc = C >> 5;
    const int c0 = (t % ntc) * 32, r0 = (t / ntc) * 32;
    const int tx = threadIdx.x & 31, ty = threadIdx.x >> 5;
#pragma unroll
    for (int i = 0; i < 32; i += 8)
        tile[ty + i][tx] = in[(size_t)(r0 + ty + i) * C + (c0 + tx)];
    __syncthreads();
#pragma unroll
    for (int i = 0; i < 32; i += 8)
        out[(size_t)(c0 + ty + i) * R + (r0 + tx)] = __float2bfloat16(tile[tx][ty + i]);
}

// concat 3x1024 fp32 biases -> [3072]
__global__ __launch_bounds__(256) void catb_k(const float* __restrict__ a,
                                              const float* __restrict__ b,
                                              const float* __restrict__ c,
                                              float* __restrict__ o) {
    const int t = blockIdx.x * 256 + threadIdx.x;
    const float* s = t < 1024 ? a : (t < 2048 ? b : c);
    o[t] = s[t & 1023];
}

// ---------------------------------------------------------------- layernorm
__device__ inline float waveRedSum(float x) {
#pragma unroll
    for (int off = 32; off; off >>= 1) x += __shfl_xor(x, off, 64);
    return x;
}

template <typename T>
__global__ __launch_bounds__(256) void layernorm_k(const T* __restrict__ in,
                                                   const float* __restrict__ g,
                                                   const float* __restrict__ bta,
                                                   bf16* __restrict__ out) {
    const int row = blockIdx.x, t = threadIdx.x;
    const int lane = t & 63, wid = t >> 6;
    const T* xr = in + (size_t)row * 1024;
    float v0, v1, v2, v3;
    if constexpr (sizeof(T) == 4) {
        float4 u = ((const float4*)xr)[t];
        v0 = u.x; v1 = u.y; v2 = u.z; v3 = u.w;
    } else {
        ushort4 u = ((const ushort4*)xr)[t];
        v0 = u2f(u.x); v1 = u2f(u.y); v2 = u2f(u.z); v3 = u2f(u.w);
    }
    __shared__ float red[8];
    float s = waveRedSum(v0 + v1 + v2 + v3);
    if (lane == 0) red[wid] = s;
    __syncthreads();
    float mu = (red[0] + red[1] + red[2] + red[3]) * (1.f / 1024.f);
    float d0 = v0 - mu, d1 = v1 - mu, d2 = v2 - mu, d3 = v3 - mu;
    float ss = waveRedSum(d0 * d0 + d1 * d1 + d2 * d2 + d3 * d3);
    if (lane == 0) red[4 + wid] = ss;
    __syncthreads();
    float var = (red[4] + red[5] + red[6] + red[7]) * (1.f / 1024.f);
    float inv = rsqrtf(var + 1e-6f);
    const int c = t * 4;
    bf16* orow = out + (size_t)row * 1024;
    orow[c + 0] = __float2bfloat16(d0 * inv * g[c + 0] + bta[c + 0]);
    orow[c + 1] = __float2bfloat16(d1 * inv * g[c + 1] + bta[c + 1]);
    orow[c + 2] = __float2bfloat16(d2 * inv * g[c + 2] + bta[c + 2]);
    orow[c + 3] = __float2bfloat16(d3 * inv * g[c + 3] + bta[c + 3]);
}

// ---------------------------------------------------------------- MFMA GEMM
// C[M,N] = A[M,K](bf16,[M][K]) @ B(bf16,[N][K] row-stride ldB) + bias.
// 128x128 tile/block, 256 thr = 2x2 waves of 64x64 (4x4 mfma 16x16x32).
// R4-verified best config: 2-buffer double-buffer, prefetch-after-barrier,
// one __syncthreads per K-step, 32KB LDS -> 5 blocks/CU (cross-block wave
// mixing is what hides the stalls at this structure; R5/R6/R7 showed deeper
// rings / bigger tiles trade occupancy for nothing). 1-D grid + bijective
// XCD swizzle (T1), setprio around MFMA cluster (T5).
template <int GELU, int RES, int ACC, typename RT, typename OT>
__global__ __launch_bounds__(256) void mgemm_k(const bf16* __restrict__ A,
                                               const bf16* __restrict__ B, int ldB,
                                               const float* __restrict__ bias,
                                               const RT* __restrict__ resid,
                                               OT* C, int M, int N, int K, int gx) {
    __shared__ bf16 As[2 * 128 * 32];
    __shared__ bf16 Bs[2 * 128 * 32];
    const int tid = threadIdx.x;
    const int lane = tid & 63, wid = tid >> 6;
    const int l16 = lane & 15, quad = lane >> 4;
    const int wm = (wid >> 1) * 64, wn = (wid & 1) * 64;
    const int nwg = gridDim.x;
    const int wg = ((blockIdx.x & 7) * (nwg >> 3)) + (blockIdx.x >> 3);
    const int m0 = (wg / gx) * 128, n0 = (wg % gx) * 128;

    const int r0 = tid >> 2, sc0 = tid & 3;
    const int lc0 = sc0 ^ ((r0 >> 1) & 3);
    const int r1 = r0 + 64;
    const int lc1 = sc0 ^ ((r1 >> 1) & 3);
    const bf16* gA0 = A + (size_t)(m0 + r0) * K + lc0 * 8;
    const bf16* gA1 = A + (size_t)(m0 + r1) * K + lc1 * 8;
    const bf16* gB0 = B + (size_t)(n0 + r0) * ldB + lc0 * 8;
    const bf16* gB1 = B + (size_t)(n0 + r1) * ldB + lc1 * 8;
    char* asb = (char*)As;
    char* bsb = (char*)Bs;
    const int lb0 = wid * 1024, lb1 = 4096 + wid * 1024;  // wave-uniform bases
    const int rdsw = (quad ^ ((l16 >> 1) & 3)) * 16;      // frag-read swizzle

    f32x4 acc[4][4] = {};
    const int nT = K >> 5;
    // prologue: stage tile 0 into buf 0
    gload_lds16(gA0, asb + lb0);
    gload_lds16(gA1, asb + lb1);
    gload_lds16(gB0, bsb + lb0);
    gload_lds16(gB1, bsb + lb1);
    __syncthreads();
    for (int t = 0; t < nT; ++t) {
        const int cur = t & 1;
        if (t + 1 < nT) {   // prefetch next K-step into other buffer
            char* ab = asb + (cur ^ 1) * 8192;
            char* bb = bsb + (cur ^ 1) * 8192;
            const int ko = (t + 1) * 32;
            gload_lds16(gA0 + ko, ab + lb0);
            gload_lds16(gA1 + ko, ab + lb1);
            gload_lds16(gB0 + ko, bb + lb0);
            gload_lds16(gB1 + ko, bb + lb1);
        }
        const char* ar = asb + cur * 8192;
        const char* br = bsb + cur * 8192;
        bf16x8 a[4], b[4];
#pragma unroll
        for (int i = 0; i < 4; ++i)
            a[i] = *(const bf16x8*)(ar + (wm + i * 16 + l16) * 64 + rdsw);
#pragma unroll
        for (int i = 0; i < 4; ++i)
            b[i] = *(const bf16x8*)(br + (wn + i * 16 + l16) * 64 + rdsw);
        __builtin_amdgcn_s_setprio(1);
#pragma unroll
        for (int mi = 0; mi < 4; ++mi)
#pragma unroll
            for (int ni = 0; ni < 4; ++ni)
                acc[mi][ni] = __builtin_amdgcn_mfma_f32_16x16x32_bf16(
                    a[mi], b[ni], acc[mi][ni], 0, 0, 0);
        __builtin_amdgcn_s_setprio(0);
        __syncthreads();   // drains prefetch (flew during compute) + lgkm
    }
#pragma unroll
    for (int mi = 0; mi < 4; ++mi) {
#pragma unroll
        for (int ni = 0; ni < 4; ++ni) {
            const int col = n0 + wn + ni * 16 + l16;
            const float bv = bias ? bias[col] : 0.f;
#pragma unroll
            for (int r = 0; r < 4; ++r) {
                const int row = m0 + wm + mi * 16 + quad * 4 + r;
                float val = acc[mi][ni][r] + bv;
                if (GELU) {
                    float z = 0.7978845608028654f * (val + 0.044715f * val * val * val);
                    float th = 1.f - 2.f / (__expf(2.f * z) + 1.f);
                    val = 0.5f * val * (1.f + th);
                }
                const size_t idx = (size_t)row * N + col;
                if (RES) val += toF(resid[idx]);
                if (ACC) val += toF(C[idx]);
                storeO(&C[idx], val);
            }
        }
    }
}

// ---------------------------------------------------------------- attention
// MFMA flash attention, register-staged K/V prefetch (T14), defer-max (T13),
// setprio (T5). 1-D grid 512: blocks c and c+256 (same CU under round-robin)
// get COMPLEMENTARY causal lengths so every CU's workload is ~equal.
__global__ __launch_bounds__(256) void attn_k(const bf16* __restrict__ q,
                                              const bf16* __restrict__ k,
                                              const bf16* __restrict__ v,
                                              bf16* __restrict__ o, int rs) {
    const int bid = blockIdx.x;
    const int u = bid & 255, top = bid >> 8;
    const int xx = u & 3;
    const int h = (u >> 2) & 15;
    const int b = top * 4 + (u >> 6);
    const int qi = top ? 3 - xx : xx;
    const int qblock = qi * 256;
    const int tid = threadIdx.x;
    const int wave = tid >> 6, lane = tid & 63;
    const int l16 = lane & 15, quad = lane >> 4;
    const int q0w = qblock + wave * 64;

    __shared__ __align__(16) bf16 Kl[64 * 64];       // [k][d] swizzled
    __shared__ __align__(16) bf16 Vt[64 * 64];       // [d][k] swizzled
    __shared__ __align__(16) bf16 Pl[4 * 64 * 64];   // per-wave [q][k] swizzled
    __shared__ __align__(16) float sc[4][64];        // per-wave per-q scratch

    bf16x8 qf[4][2];
#pragma unroll
    for (int ni = 0; ni < 4; ++ni) {
        const int row = q0w + ni * 16 + l16;
        const bf16* qp = q + ((size_t)b * 1024 + row) * rs + h * 64;
#pragma unroll
        for (int kc = 0; kc < 2; ++kc)
            qf[ni][kc] = *(const bf16x8*)(qp + kc * 32 + quad * 8);
    }

    f32x4 acc[4][4] = {};     // O: row q = mi*16+quad*4+r, col d = ni*16+l16
    float mrun[4], lrun[4];
#pragma unroll
    for (int ni = 0; ni < 4; ++ni) { mrun[ni] = -1e30f; lrun[ni] = 0.f; }

    const int NT = qi * 4 + 4;
    const int myNT = qi * 4 + wave + 1;

    const int kr_ = tid >> 3, kch = tid & 7;              // K rows kr_, kr_+32
    const int vr_ = (tid >> 3) * 2, vdb = (tid & 7) * 8;  // V rows vr_, vr_+1
    uint4 kA, kB, vA, vB;
    {   // prefetch tile 0
        const size_t gk = ((size_t)b * 1024 + 0 + kr_) * rs + h * 64 + kch * 8;
        kA = *(const uint4*)(k + gk);
        kB = *(const uint4*)(k + gk + (size_t)32 * rs);
        const size_t gv = ((size_t)b * 1024 + 0 + vr_) * rs + h * 64 + vdb;
        vA = *(const uint4*)(v + gv);
        vB = *(const uint4*)(v + gv + rs);
    }

    for (int t = 0; t < NT; ++t) {
        wgbar();   // all waves done reading Kl/Vt from previous tile
        // ---- write prefetched K (row-major, swizzled) ----
        *(uint4*)((char*)Kl + swzb(kr_, kch * 16)) = kA;
        *(uint4*)((char*)Kl + swzb(kr_ + 32, kch * 16)) = kB;
        // ---- write prefetched V transposed (Vt[d][k], swizzled) ----
        {
            const unsigned aw[4] = {vA.x, vA.y, vA.z, vA.w};
            const unsigned bw[4] = {vB.x, vB.y, vB.z, vB.w};
#pragma unroll
            for (int j = 0; j < 8; ++j) {
                const unsigned lo = (aw[j >> 1] >> ((j & 1) * 16)) & 0xffffu;
                const unsigned hi = (bw[j >> 1] >> ((j & 1) * 16)) & 0xffffu;
                *(unsigned*)((char*)Vt + swzb(vdb + j, vr_ * 2)) = lo | (hi << 16);
            }
        }
        // ---- issue next tile's global loads (fly across compute) ----
        if (t + 1 < NT) {
            const int j1 = (t + 1) * 64;
            const size_t gk = ((size_t)b * 1024 + j1 + kr_) * rs + h * 64 + kch * 8;
            kA = *(const uint4*)(k + gk);
            kB = *(const uint4*)(k + gk + (size_t)32 * rs);
            const size_t gv = ((size_t)b * 1024 + j1 + vr_) * rs + h * 64 + vdb;
            vA = *(const uint4*)(v + gv);
            vB = *(const uint4*)(v + gv + rs);
        }
        wgbar();   // staged tile visible to all waves
        if (t < myNT) {
            const int j0 = t * 64;
            // ---- S^T = K @ Q^T ----
            f32x4 st[4][4] = {};
#pragma unroll
            for (int kc = 0; kc < 2; ++kc) {
                bf16x8 kf[4];
#pragma unroll
                for (int mi = 0; mi < 4; ++mi)
                    kf[mi] = *(const bf16x8*)((char*)Kl +
                             swzb(mi * 16 + l16, kc * 64 + quad * 16));
                __builtin_amdgcn_s_setprio(1);
#pragma unroll
                for (int mi = 0; mi < 4; ++mi)
#pragma unroll
                    for (int ni = 0; ni < 4; ++ni)
                        st[mi][ni] = __builtin_amdgcn_mfma_f32_16x16x32_bf16(
                            kf[mi], qf[ni][kc], st[mi][ni], 0, 0, 0);
                __builtin_amdgcn_s_setprio(0);
            }
            if (j0 == q0w) {  // causal mask, diagonal tile only
#pragma unroll
                for (int mi = 0; mi < 4; ++mi)
#pragma unroll
                    for (int ni = 0; ni < 4; ++ni)
#pragma unroll
                        for (int r = 0; r < 4; ++r)
                            if (mi * 16 + quad * 4 + r > ni * 16 + l16)
                                st[mi][ni][r] = -1e30f;
            }
            // ---- tile max per q (tree + cross-quad reduce) ----
            float mx[4];
#pragma unroll
            for (int ni = 0; ni < 4; ++ni) {
                float a0 = fmaxf(st[0][ni][0], st[0][ni][1]);
                float a1 = fmaxf(st[0][ni][2], st[0][ni][3]);
                float a2 = fmaxf(st[1][ni][0], st[1][ni][1]);
                float a3 = fmaxf(st[1][ni][2], st[1][ni][3]);
                float a4 = fmaxf(st[2][ni][0], st[2][ni][1]);
                float a5 = fmaxf(st[2][ni][2], st[2][ni][3]);
                float a6 = fmaxf(st[3][ni][0], st[3][ni][1]);
                float a7 = fmaxf(st[3][ni][2], st[3][ni][3]);
                float m_ = fmaxf(fmaxf(fmaxf(a0, a1), fmaxf(a2, a3)),
                                 fmaxf(fmaxf(a4, a5), fmaxf(a6, a7)));
                m_ = fmaxf(m_, __shfl_xor(m_, 16, 64));
                m_ = fmaxf(m_, __shfl_xor(m_, 32, 64));
                mx[ni] = m_;
            }
            // ---- defer-max (T13): rescale only if growth > 64 raw ----
            const bool need = (mx[0] > mrun[0] + 64.f) | (mx[1] > mrun[1] + 64.f) |
                              (mx[2] > mrun[2] + 64.f) | (mx[3] > mrun[3] + 64.f);
            if (__any(need)) {
                float fac[4];
#pragma unroll
                for (int ni = 0; ni < 4; ++ni) {
                    const float nm = (mx[ni] > mrun[ni] + 64.f) ? mx[ni] : mrun[ni];
                    fac[ni] = __expf((mrun[ni] - nm) * 0.125f);
                    mrun[ni] = nm;
                    lrun[ni] *= fac[ni];
                }
                if (quad == 0)
#pragma unroll
                    for (int ni = 0; ni < 4; ++ni) sc[wave][ni * 16 + l16] = fac[ni];
#pragma unroll
                for (int mi = 0; mi < 4; ++mi) {
                    const f32x4 f4 = *(const f32x4*)&sc[wave][mi * 16 + quad * 4];
#pragma unroll
                    for (int ni = 0; ni < 4; ++ni)
#pragma unroll
                        for (int r = 0; r < 4; ++r) acc[mi][ni][r] *= f4[r];
                }
            }
            // ---- exp + sum (4 parallel chains, tree finish) ----
#pragma unroll
            for (int ni = 0; ni < 4; ++ni) {
                const float mm = mrun[ni];
                float t0 = 0.f, t1 = 0.f, t2 = 0.f, t3 = 0.f;
#pragma unroll
                for (int mi = 0; mi < 4; ++mi) {
                    float p0 = __expf((st[mi][ni][0] - mm) * 0.125f);
                    float p1 = __expf((st[mi][ni][1] - mm) * 0.125f);
                    float p2 = __expf((st[mi][ni][2] - mm) * 0.125f);
                    float p3 = __expf((st[mi][ni][3] - mm) * 0.125f);
                    st[mi][ni][0] = p0; st[mi][ni][1] = p1;
                    st[mi][ni][2] = p2; st[mi][ni][3] = p3;
                    t0 += p0; t1 += p1; t2 += p2; t3 += p3;
                }
                float ls = (t0 + t1) + (t2 + t3);
                ls += __shfl_xor(ls, 16, 64);
                ls += __shfl_xor(ls, 32, 64);
                lrun[ni] += ls;
            }
            // ---- write P to per-wave LDS [q][k] (b64 packed, swizzled) ----
            char* Pb = (char*)Pl + wave * 8192;
#pragma unroll
            for (int ni = 0; ni < 4; ++ni) {
                const int qrow = ni * 16 + l16;
#pragma unroll
                for (int mi = 0; mi < 4; ++mi) {
                    union { bf16 bv[4]; uint2 u2; } pk;
#pragma unroll
                    for (int r = 0; r < 4; ++r)
                        pk.bv[r] = __float2bfloat16(st[mi][ni][r]);
                    *(uint2*)(Pb + swzb(qrow, mi * 32 + quad * 8)) = pk.u2;
                }
            }
            // ---- O += P @ V ----
#pragma unroll
            for (int kc = 0; kc < 2; ++kc) {
                bf16x8 pf[4], vf[4];
#pragma unroll
                for (int mi = 0; mi < 4; ++mi)
                    pf[mi] = *(const bf16x8*)(Pb +
                             swzb(mi * 16 + l16, kc * 64 + quad * 16));
#pragma unroll
                for (int ni = 0; ni < 4; ++ni)
                    vf[ni] = *(const bf16x8*)((char*)Vt +
                             swzb(ni * 16 + l16, kc * 64 + quad * 16));
                __builtin_amdgcn_s_setprio(1);
#pragma unroll
                for (int mi = 0; mi < 4; ++mi)
#pragma unroll
                    for (int ni = 0; ni < 4; ++ni)
                        acc[mi][ni] = __builtin_amdgcn_mfma_f32_16x16x32_bf16(
                            pf[mi], vf[ni], acc[mi][ni], 0, 0, 0);
                __builtin_amdgcn_s_setprio(0);
            }
        }
    }
    if (quad == 0)
#pragma unroll
        for (int ni = 0; ni < 4; ++ni) sc[wave][ni * 16 + l16] = lrun[ni];
#pragma unroll
    for (int mi = 0; mi < 4; ++mi) {
        const f32x4 l4 = *(const f32x4*)&sc[wave][mi * 16 + quad * 4];
#pragma unroll
        for (int r = 0; r < 4; ++r) {
            const float inv = 1.f / l4[r];
            const int row = q0w + mi * 16 + quad * 4 + r;
            bf16* orow = o + ((size_t)b * 1024 + row) * 1024 + h * 64;
#pragma unroll
            for (int ni = 0; ni < 4; ++ni)
                orow[ni * 16 + l16] = __float2bfloat16(acc[mi][ni][r] * inv);
        }
    }
}

// ---------------------------------------------------------------- launch
extern "C" void kernel_launch(void* const* d_in, const int* in_sizes, int n_in,
                              void* d_out, int out_size, void* d_ws, size_t ws_size,
                              hipStream_t stream) {
    (void)out_size; (void)ws_size;
    const float* x = (const float*)d_in[0];
    const int base = (n_in >= 18 && in_sizes[1] > 4096) ? 2 : 1;  // skip mask
    const float* ln1s = (const float*)d_in[base + 0];
    const float* ln1b = (const float*)d_in[base + 1];
    const float* wq   = (const float*)d_in[base + 2];
    const float* bq   = (const float*)d_in[base + 3];
    const float* wk   = (const float*)d_in[base + 4];
    const float* bk   = (const float*)d_in[base + 5];
    const float* wv   = (const float*)d_in[base + 6];
    const float* bv   = (const float*)d_in[base + 7];
    const float* wo   = (const float*)d_in[base + 8];
    const float* bo   = (const float*)d_in[base + 9];
    const float* ln2s = (const float*)d_in[base + 10];
    const float* ln2b = (const float*)d_in[base + 11];
    const float* w1   = (const float*)d_in[base + 12];
    const float* b1   = (const float*)d_in[base + 13];
    const float* w2   = (const float*)d_in[base + 14];
    const float* b2   = (const float*)d_in[base + 15];
    float* out = (float*)d_out;   // fp32 output (also used as scratch)

    // Workspace map (64MB), phase-disjoint lifetimes:
    //   ws[0,16)  h (LN1) -> ao (attn out) -> h2 (LN2 out)
    //   ws[16,64) qkv [8192][3072] bf16 -> woT[16,18) -> f1c[16,48)
    //   ws[48,56) w1T  (after attn)      ws[56,64) w2T
    // d_out (32MB fp32) as scratch early:
    //   out[0,6MB) wqkvT bf16 [3072][1024]; out[8MB) bqkv [3072] fp32
    //   -> x2 fp32 (wo GEMM, residual) -> final output (FFN2 ACC)
    char* ws = (char*)d_ws;
    char* oc = (char*)d_out;
    const size_t MB = 1ull << 20;
    bf16* h     = (bf16*)(ws + 0 * MB);
    bf16* qkv   = (bf16*)(ws + 16 * MB);
    bf16* ao    = (bf16*)(ws + 0 * MB);
    bf16* h2    = (bf16*)(ws + 0 * MB);
    bf16* woT   = (bf16*)(ws + 16 * MB);
    bf16* f1c   = (bf16*)(ws + 16 * MB);   // [8192][2048] bf16, 32MB
    bf16* w1T   = (bf16*)(ws + 48 * MB);
    bf16* w2T   = (bf16*)(ws + 56 * MB);
    bf16* wqkvT = (bf16*)(oc + 0 * MB);
    float* bqkv = (float*)(oc + 8 * MB);

    const dim3 tb(256);

    layernorm_k<float><<<8192, tb, 0, stream>>>(x, ln1s, ln1b, h);
    qkvT_k<<<dim3(32, 32, 3), tb, 0, stream>>>(wq, wk, wv, wqkvT);
    catb_k<<<12, tb, 0, stream>>>(bq, bk, bv, bqkv);
    // fused QKV: [8192][3072] = h @ wqkvT   (128x128 tiles: 64x24 = 1536 wg)
    mgemm_k<0, 0, 0, float, bf16><<<1536, tb, 0, stream>>>(
        h, wqkvT, 1024, bqkv, nullptr, qkv, 8192, 3072, 1024, 24);
    attn_k<<<512, tb, 0, stream>>>(qkv, qkv + 1024, qkv + 2048, ao, 3072);
    // qkv dead: transpose remaining weights (one batched launch)
    wT_k<<<9216, tb, 0, stream>>>(wo, w1, w2, woT, w1T, w2T);
    // x2 = ao @ woT + bo + x  -> fp32 directly into out (residual stream)
    mgemm_k<0, 1, 0, float, float><<<512, tb, 0, stream>>>(
        ao, woT, 1024, bo, x, out, 8192, 1024, 1024, 8);
    layernorm_k<float><<<8192, tb, 0, stream>>>(out, ln2s, ln2b, h2);
    // FFN in 2 chunks of 2048; FFN2 accumulates onto out (holds x2)
    for (int c = 0; c < 2; ++c) {
        mgemm_k<1, 0, 0, float, bf16><<<1024, tb, 0, stream>>>(
            h2, w1T + (size_t)c * 2048 * 1024, 1024, b1 + c * 2048, nullptr,
            f1c, 8192, 2048, 1024, 16);
        mgemm_k<0, 0, 1, float, float><<<512, tb, 0, stream>>>(
            f1c, w2T + c * 2048, 4096, c ? nullptr : b2, nullptr,
            out, 8192, 1024, 2048, 8);
    }
}